// Round 9
// baseline (257.769 us; speedup 1.0000x reference)
//
#include <hip/hip_runtime.h>

typedef __bf16 bf16x8 __attribute__((ext_vector_type(8)));
typedef float f32x4 __attribute__((ext_vector_type(4)));
typedef unsigned short us8 __attribute__((ext_vector_type(8)));

#define GAS __attribute__((address_space(1)))
#define LAS __attribute__((address_space(3)))

__device__ __forceinline__ unsigned short f32_to_bf16(float f) {
    unsigned int u = __float_as_uint(f);
    u += 0x7FFFu + ((u >> 16) & 1u);   // round-to-nearest-even
    return (unsigned short)(u >> 16);
}

__device__ __forceinline__ float bf16_to_f32(unsigned short h) {
    return __uint_as_float((unsigned int)h << 16);
}

__device__ __forceinline__ void load16(const unsigned short* g, unsigned short* l) {
    // async global->LDS, 16B per lane; LDS dest is wave-uniform base + lane*16
    __builtin_amdgcn_global_load_lds((GAS unsigned int*)g, (LAS unsigned int*)l, 16, 0, 0);
}

// ---------------------------------------------------------------------------
// prep (1024 threads): blocks [0,1536) convert x fp32->bf16 float4-wide;
// blocks [1536,3264) transpose the three 768x768 weights to bf16;
// block 3264 zeroes lsum[2*4096].
// ---------------------------------------------------------------------------
__global__ __launch_bounds__(1024) void prep(
    const float* __restrict__ x, unsigned short* __restrict__ Xbf,
    const float* __restrict__ W0, const float* __restrict__ W1, const float* __restrict__ W2,
    unsigned short* __restrict__ T0, unsigned short* __restrict__ T1, unsigned short* __restrict__ T2,
    float* __restrict__ lsum)
{
    __shared__ float tile[32][33];
    const int id = blockIdx.x;
    const int t = threadIdx.x;
    if (id < 1536) {
        int i = id * 1024 + t;
        float4 v = ((const float4*)x)[i];
        ushort4 o;
        o.x = f32_to_bf16(v.x); o.y = f32_to_bf16(v.y);
        o.z = f32_to_bf16(v.z); o.w = f32_to_bf16(v.w);
        ((ushort4*)Xbf)[i] = o;
    } else if (id < 3264) {
        const int tid = id - 1536;               // 0..1727
        const int z = tid / 576, rem = tid % 576;
        const int by = rem / 24, bx = rem % 24;
        const float* W = (z == 0) ? W0 : (z == 1) ? W1 : W2;
        unsigned short* T = (z == 0) ? T0 : (z == 1) ? T1 : T2;
        const int r0 = by * 32, c0 = bx * 32;
        const int tx = t & 31, ty = t >> 5;      // 32x32
        tile[ty][tx] = W[(size_t)(r0 + ty) * 768 + c0 + tx];
        __syncthreads();
        T[(size_t)(c0 + ty) * 768 + r0 + tx] = f32_to_bf16(tile[tx][ty]);
    } else {
        float4 z4 = {0.f, 0.f, 0.f, 0.f};
        ((float4*)lsum)[t] = z4;
        ((float4*)lsum)[t + 1024] = z4;          // 8192 floats total
    }
}

// ---------------------------------------------------------------------------
// qk2: Q and K in ONE exact-fill launch. C = Xbf[8192,768] . Wqk^T, where
// Wqk = WqT||WkT stacked rows [1536,768] (contiguous allocations).
// v4 monolithic core, BM=256 x BN=192, NT=12, ring-2 LDS (112 KiB),
// counted vmcnt(7). 256 blocks = 32 mb x 8 nb; nb 0-3 -> Qb, 4-7 -> Kb.
// XCD swizzle: mb = xcd*4 + (local>>3), nb = local&7 -> A panels L2-shared 8x.
// ---------------------------------------------------------------------------
__global__ __launch_bounds__(512) void qk2(
    const unsigned short* __restrict__ Xbf,
    const unsigned short* __restrict__ Wqk,
    unsigned short* __restrict__ Qb,
    unsigned short* __restrict__ Kb)
{
    const int f = blockIdx.x;           // 0..255
    const int xcd = f & 7;
    const int local = f >> 3;           // 0..31
    const int mb = xcd * 4 + (local >> 3);   // 0..31
    const int nb = local & 7;                // 0..7
    const unsigned short* A = Xbf;
    const unsigned short* B = Wqk;
    unsigned short* C = (nb < 4) ? Qb : Kb;
    const int m0 = mb * 256;
    const int n0 = nb * 192;            // row into Wqk (0..1344)
    const int c0 = (nb & 3) * 192;      // col into Qb/Kb
    const int lda = 768, ldb = 768, ldc = 768;
    constexpr int NT = 12;

    __shared__ unsigned short As[2][256 * 64];
    __shared__ unsigned short Bs[2][192 * 64];

    const int t = threadIdx.x;
    const int lane = t & 63;
    const int w = t >> 6;
    const int wm = (w >> 2) * 128;      // 0/128 (8 mi frags)
    const int wn = (w & 3) * 48;        // 0..144 (3 ni frags)
    const int r15 = lane & 15;
    const int qa = lane >> 4;

    const unsigned short* srcA[4];
    int dstA[4];
#pragma unroll
    for (int i = 0; i < 4; ++i) {
        const int c = i * 512 + t;
        const int row = c >> 3;
        const int cc = (c & 7) ^ (row & 7);
        srcA[i] = A + (size_t)(m0 + row) * lda + cc * 8;
        dstA[i] = c * 8;
    }
    const unsigned short* srcB[3];
    int dstB[3];
#pragma unroll
    for (int i = 0; i < 3; ++i) {
        const int c = i * 512 + t;
        const int row = c >> 3;
        const int cc = (c & 7) ^ (row & 7);
        srcB[i] = B + (size_t)(n0 + row) * ldb + cc * 8;
        dstB[i] = c * 8;
    }

    auto stage = [&](int buf, int kbase) {
#pragma unroll
        for (int i = 0; i < 4; ++i) load16(srcA[i] + kbase, &As[buf][dstA[i]]);
#pragma unroll
        for (int i = 0; i < 3; ++i) load16(srcB[i] + kbase, &Bs[buf][dstB[i]]);
    };

    int offA[8][2], offB[3][2];
#pragma unroll
    for (int mi = 0; mi < 8; ++mi) {
        const int row = wm + mi * 16 + r15;
#pragma unroll
        for (int ks = 0; ks < 2; ++ks)
            offA[mi][ks] = row * 64 + (((ks << 2) + qa) ^ (row & 7)) * 8;
    }
#pragma unroll
    for (int ni = 0; ni < 3; ++ni) {
        const int row = wn + ni * 16 + r15;
#pragma unroll
        for (int ks = 0; ks < 2; ++ks)
            offB[ni][ks] = row * 64 + (((ks << 2) + qa) ^ (row & 7)) * 8;
    }

    f32x4 acc[8][3];
#pragma unroll
    for (int i = 0; i < 8; ++i)
#pragma unroll
        for (int j = 0; j < 3; ++j) acc[i][j] = (f32x4){0.f, 0.f, 0.f, 0.f};

    stage(0, 0);
    stage(1, 64);

    for (int tt = 0; tt < NT; ++tt) {
        const int b = tt & 1;
        if (tt == NT - 1) {
            asm volatile("s_waitcnt vmcnt(0)" ::: "memory");
        } else {
            asm volatile("s_waitcnt vmcnt(7)" ::: "memory");
        }
        __builtin_amdgcn_s_barrier();

#pragma unroll
        for (int ks = 0; ks < 2; ++ks) {
            bf16x8 aA[8], bB[3];
#pragma unroll
            for (int i = 0; i < 8; ++i)
                aA[i] = *(const bf16x8*)&As[b][offA[i][ks]];
#pragma unroll
            for (int ni = 0; ni < 3; ++ni)
                bB[ni] = *(const bf16x8*)&Bs[b][offB[ni][ks]];
#pragma unroll
            for (int i = 0; i < 8; ++i)
#pragma unroll
                for (int ni = 0; ni < 3; ++ni)
                    acc[i][ni] = __builtin_amdgcn_mfma_f32_16x16x32_bf16(
                        aA[i], bB[ni], acc[i][ni], 0, 0, 0);
        }

        asm volatile("" ::: "memory");
        __builtin_amdgcn_s_barrier();

        if (tt + 2 < NT) stage(b, (tt + 2) << 6);
    }

    const int cr = (lane >> 4) * 4;
#pragma unroll
    for (int mi = 0; mi < 8; ++mi)
#pragma unroll
        for (int ni = 0; ni < 3; ++ni) {
            const int gm = m0 + wm + mi * 16 + cr;
            const int gn = c0 + wn + ni * 16 + r15;
#pragma unroll
            for (int r = 0; r < 4; ++r)
                C[(size_t)(gm + r) * ldc + gn] = f32_to_bf16(acc[mi][ni][r]);
        }
}

// ---------------------------------------------------------------------------
// vt2: V^T = WvT[768,768] . Xbf^T -> [768, 8192]. v4 core, BM=192 x BN=128,
// NT=12, ring-2 LDS (80 KiB), counted vmcnt(5). 256 blocks = 4 mb x 64 nb =
// exact fill. XCD swizzle: nb = xcd*8 + (local>>2), mb = local&3 -> Xbf
// panels L2-shared 4x.
// ---------------------------------------------------------------------------
__global__ __launch_bounds__(512) void vt2(
    const unsigned short* __restrict__ WvT,
    const unsigned short* __restrict__ Xbf,
    unsigned short* __restrict__ Vt)
{
    const int f = blockIdx.x;           // 0..255
    const int xcd = f & 7;
    const int local = f >> 3;           // 0..31
    const int nb = xcd * 8 + (local >> 2);   // 0..63
    const int mb = local & 3;                // 0..3
    const unsigned short* A = WvT;
    const unsigned short* B = Xbf;
    unsigned short* C = Vt;
    const int m0 = mb * 192;
    const int n0 = nb * 128;
    const int lda = 768, ldb = 768, ldc = 8192;
    constexpr int NT = 12;

    __shared__ unsigned short As[2][192 * 64];
    __shared__ unsigned short Bs[2][128 * 64];

    const int t = threadIdx.x;
    const int lane = t & 63;
    const int w = t >> 6;
    const int wm = (w >> 2) * 96;       // 0/96 (6 mi frags)
    const int wn = (w & 3) * 32;        // 0..96 (2 ni frags)
    const int r15 = lane & 15;
    const int qa = lane >> 4;

    const unsigned short* srcA[3];
    int dstA[3];
#pragma unroll
    for (int i = 0; i < 3; ++i) {
        const int c = i * 512 + t;
        const int row = c >> 3;
        const int cc = (c & 7) ^ (row & 7);
        srcA[i] = A + (size_t)(m0 + row) * lda + cc * 8;
        dstA[i] = c * 8;
    }
    const unsigned short* srcB[2];
    int dstB[2];
#pragma unroll
    for (int i = 0; i < 2; ++i) {
        const int c = i * 512 + t;
        const int row = c >> 3;
        const int cc = (c & 7) ^ (row & 7);
        srcB[i] = B + (size_t)(n0 + row) * ldb + cc * 8;
        dstB[i] = c * 8;
    }

    auto stage = [&](int buf, int kbase) {
#pragma unroll
        for (int i = 0; i < 3; ++i) load16(srcA[i] + kbase, &As[buf][dstA[i]]);
#pragma unroll
        for (int i = 0; i < 2; ++i) load16(srcB[i] + kbase, &Bs[buf][dstB[i]]);
    };

    int offA[6][2], offB[2][2];
#pragma unroll
    for (int mi = 0; mi < 6; ++mi) {
        const int row = wm + mi * 16 + r15;
#pragma unroll
        for (int ks = 0; ks < 2; ++ks)
            offA[mi][ks] = row * 64 + (((ks << 2) + qa) ^ (row & 7)) * 8;
    }
#pragma unroll
    for (int ni = 0; ni < 2; ++ni) {
        const int row = wn + ni * 16 + r15;
#pragma unroll
        for (int ks = 0; ks < 2; ++ks)
            offB[ni][ks] = row * 64 + (((ks << 2) + qa) ^ (row & 7)) * 8;
    }

    f32x4 acc[6][2];
#pragma unroll
    for (int i = 0; i < 6; ++i)
#pragma unroll
        for (int j = 0; j < 2; ++j) acc[i][j] = (f32x4){0.f, 0.f, 0.f, 0.f};

    stage(0, 0);
    stage(1, 64);

    for (int tt = 0; tt < NT; ++tt) {
        const int b = tt & 1;
        if (tt == NT - 1) {
            asm volatile("s_waitcnt vmcnt(0)" ::: "memory");
        } else {
            asm volatile("s_waitcnt vmcnt(5)" ::: "memory");
        }
        __builtin_amdgcn_s_barrier();

#pragma unroll
        for (int ks = 0; ks < 2; ++ks) {
            bf16x8 aA[6], bB[2];
#pragma unroll
            for (int i = 0; i < 6; ++i)
                aA[i] = *(const bf16x8*)&As[b][offA[i][ks]];
#pragma unroll
            for (int ni = 0; ni < 2; ++ni)
                bB[ni] = *(const bf16x8*)&Bs[b][offB[ni][ks]];
#pragma unroll
            for (int i = 0; i < 6; ++i)
#pragma unroll
                for (int ni = 0; ni < 2; ++ni)
                    acc[i][ni] = __builtin_amdgcn_mfma_f32_16x16x32_bf16(
                        aA[i], bB[ni], acc[i][ni], 0, 0, 0);
        }

        asm volatile("" ::: "memory");
        __builtin_amdgcn_s_barrier();

        if (tt + 2 < NT) stage(b, (tt + 2) << 6);
    }

    const int cr = (lane >> 4) * 4;
#pragma unroll
    for (int mi = 0; mi < 6; ++mi)
#pragma unroll
        for (int ni = 0; ni < 2; ++ni) {
            const int gm = m0 + wm + mi * 16 + cr;
            const int gn = n0 + wn + ni * 16 + r15;
#pragma unroll
            for (int r = 0; r < 4; ++r)
                C[(size_t)(gm + r) * ldc + gn] = f32_to_bf16(acc[mi][ni][r]);
        }
}

// ---------------------------------------------------------------------------
// Sexp = exp(alpha * Q.K^T) bf16, 256^2 v4 core + fused f32 row sums.
// __launch_bounds__(512): LDS (128 KiB) already limits to 1 block/CU, so no
// VGPR cap -> the fused epilogue (exp + store + accumulate + 16-lane shfl +
// atomicAdd per row) fits without spill (the R5 regression was the (512,2)
// 128-VGPR cap, not the epilogue itself).
// ---------------------------------------------------------------------------
__global__ __launch_bounds__(512) void gemm_s_exp2(
    const unsigned short* __restrict__ Q, const unsigned short* __restrict__ Kb,
    unsigned short* __restrict__ Sexp, float* __restrict__ lsum, float alpha)
{
    const int f = blockIdx.x;            // 0..511
    const int xcd = f & 7;
    const int local = f >> 3;            // 0..63
    const int x = (xcd & 1) * 8 + (local & 7);
    const int y = ((xcd >> 1) & 1) * 8 + (local >> 3);
    const int bb = xcd >> 2;
    const unsigned short* A = Q + (size_t)bb * 3145728;
    const unsigned short* B = Kb + (size_t)bb * 3145728;
    unsigned short* C = Sexp + (size_t)bb * 16777216;
    float* ls = lsum + bb * 4096;
    const int m0 = y * 256, n0 = x * 256;
    const int lda = 768, ldb = 768, ldc = 4096;
    constexpr int NT = 12;

    __shared__ unsigned short As[2][256 * 64];
    __shared__ unsigned short Bs[2][256 * 64];

    const int t = threadIdx.x;          // 0..511
    const int lane = t & 63;
    const int w = t >> 6;               // 0..7
    const int wm = (w >> 2) * 128;      // 0 / 128
    const int wn = (w & 3) * 64;        // 0..192
    const int r15 = lane & 15;
    const int qa = lane >> 4;           // 0..3

    const unsigned short* srcA[4];
    const unsigned short* srcB[4];
    int dst[4];
#pragma unroll
    for (int i = 0; i < 4; ++i) {
        const int c = i * 512 + t;
        const int row = c >> 3;
        const int cc = (c & 7) ^ (row & 7);
        srcA[i] = A + (size_t)(m0 + row) * lda + cc * 8;
        srcB[i] = B + (size_t)(n0 + row) * ldb + cc * 8;
        dst[i] = c * 8;
    }

    auto stage = [&](int buf, int kbase) {
#pragma unroll
        for (int i = 0; i < 4; ++i)
            load16(srcA[i] + kbase, &As[buf][dst[i]]);
#pragma unroll
        for (int i = 0; i < 4; ++i)
            load16(srcB[i] + kbase, &Bs[buf][dst[i]]);
    };

    int offA[8][2], offB[4][2];
#pragma unroll
    for (int mi = 0; mi < 8; ++mi) {
        const int row = wm + mi * 16 + r15;
#pragma unroll
        for (int ks = 0; ks < 2; ++ks)
            offA[mi][ks] = row * 64 + (((ks << 2) + qa) ^ (row & 7)) * 8;
    }
#pragma unroll
    for (int ni = 0; ni < 4; ++ni) {
        const int row = wn + ni * 16 + r15;
#pragma unroll
        for (int ks = 0; ks < 2; ++ks)
            offB[ni][ks] = row * 64 + (((ks << 2) + qa) ^ (row & 7)) * 8;
    }

    f32x4 acc[8][4];
#pragma unroll
    for (int i = 0; i < 8; ++i)
#pragma unroll
        for (int j = 0; j < 4; ++j) acc[i][j] = (f32x4){0.f, 0.f, 0.f, 0.f};

    stage(0, 0);
    stage(1, 64);

    for (int tt = 0; tt < NT; ++tt) {
        const int b = tt & 1;
        if (tt == NT - 1) {
            asm volatile("s_waitcnt vmcnt(0)" ::: "memory");
        } else {
            asm volatile("s_waitcnt vmcnt(8)" ::: "memory");
        }
        __builtin_amdgcn_s_barrier();

#pragma unroll
        for (int ks = 0; ks < 2; ++ks) {
            bf16x8 aA[8], bB[4];
#pragma unroll
            for (int i = 0; i < 8; ++i)
                aA[i] = *(const bf16x8*)&As[b][offA[i][ks]];
#pragma unroll
            for (int ni = 0; ni < 4; ++ni)
                bB[ni] = *(const bf16x8*)&Bs[b][offB[ni][ks]];
#pragma unroll
            for (int i = 0; i < 8; ++i)
#pragma unroll
                for (int ni = 0; ni < 4; ++ni)
                    acc[i][ni] = __builtin_amdgcn_mfma_f32_16x16x32_bf16(
                        aA[i], bB[ni], acc[i][ni], 0, 0, 0);
        }

        asm volatile("" ::: "memory");
        __builtin_amdgcn_s_barrier();

        if (tt + 2 < NT) stage(b, (tt + 2) << 6);
    }

    // fused epilogue: exp + store + f32 row sums (pre-rounding), shfl-reduce
    // across the 16 lanes of each row, one atomicAdd per row.
    const int cr = (lane >> 4) * 4;
#pragma unroll
    for (int mi = 0; mi < 8; ++mi) {
        const int gm = m0 + wm + mi * 16 + cr;
        float rs0 = 0.f, rs1 = 0.f, rs2 = 0.f, rs3 = 0.f;
#pragma unroll
        for (int ni = 0; ni < 4; ++ni) {
            const int gn = n0 + wn + ni * 16 + r15;
            float v0 = __expf(alpha * acc[mi][ni][0]);
            float v1 = __expf(alpha * acc[mi][ni][1]);
            float v2 = __expf(alpha * acc[mi][ni][2]);
            float v3 = __expf(alpha * acc[mi][ni][3]);
            C[(size_t)(gm + 0) * ldc + gn] = f32_to_bf16(v0);
            C[(size_t)(gm + 1) * ldc + gn] = f32_to_bf16(v1);
            C[(size_t)(gm + 2) * ldc + gn] = f32_to_bf16(v2);
            C[(size_t)(gm + 3) * ldc + gn] = f32_to_bf16(v3);
            rs0 += v0; rs1 += v1; rs2 += v2; rs3 += v3;
        }
#pragma unroll
        for (int m = 1; m < 16; m <<= 1) {
            rs0 += __shfl_xor(rs0, m, 64);
            rs1 += __shfl_xor(rs1, m, 64);
            rs2 += __shfl_xor(rs2, m, 64);
            rs3 += __shfl_xor(rs3, m, 64);
        }
        if (r15 == 0) {
            atomicAdd(&ls[gm + 0], rs0);
            atomicAdd(&ls[gm + 1], rs1);
            atomicAdd(&ls[gm + 2], rs2);
            atomicAdd(&ls[gm + 3], rs3);
        }
    }
}

// ---------------------------------------------------------------------------
// Fused O-GEMM + normalize: out = (Sexp . V) / lsum, fp32. 24 MFMA/tile
// (ones-MFMA removed -- it cost +33% matrix-pipe work, R8 post-mortem).
// BM=128 x BN=192 -> 256 blocks exact fill. Ring-3 LDS, counted vmcnt(10/5/0).
// R8's row-sharing XCD swizzle kept (FETCH 57 MB).
// ---------------------------------------------------------------------------
__global__ __launch_bounds__(512) void gemm_out(
    const unsigned short* __restrict__ P, const unsigned short* __restrict__ Vt,
    const float* __restrict__ lsum, float* __restrict__ out)
{
    const int f = blockIdx.x;           // 0..255
    const int xcd = f & 7;
    const int local = f >> 3;           // 0..31
    const int nb = local & 3;           // n-block (same XCD for all 4)
    const int rg = xcd * 8 + (local >> 2);   // row group 0..63
    const int batch = rg >> 5;
    const int mb = rg & 31;             // m-block 0..31
    const unsigned short* A = P + (size_t)batch * 16777216;
    const unsigned short* B = Vt + (size_t)batch * 4096;
    const float* ls = lsum + batch * 4096;
    float* C = out + (size_t)batch * 3145728;
    const int m0 = mb * 128, n0 = nb * 192;
    const int lda = 4096, ldb = 8192;
    constexpr int NT = 64;

    __shared__ unsigned short As[3][128 * 64];
    __shared__ unsigned short Bs[3][192 * 64];

    const int t = threadIdx.x;          // 0..511
    const int lane = t & 63;
    const int w = t >> 6;               // 0..7
    const int wm = (w >> 2) * 64;       // 0 / 64
    const int wn = (w & 3) * 48;        // 0..144
    const int r15 = lane & 15;
    const int qa = lane >> 4;           // 0..3

    const unsigned short* srcA[2];
    int dstA[2];
#pragma unroll
    for (int i = 0; i < 2; ++i) {
        const int c = i * 512 + t;
        const int row = c >> 3;
        const int cc = (c & 7) ^ (row & 7);
        srcA[i] = A + (size_t)(m0 + row) * lda + cc * 8;
        dstA[i] = c * 8;
    }
    const unsigned short* srcB[3];
    int dstB[3];
#pragma unroll
    for (int i = 0; i < 3; ++i) {
        const int c = i * 512 + t;
        const int row = c >> 3;
        const int cc = (c & 7) ^ (row & 7);
        srcB[i] = B + (size_t)(n0 + row) * ldb + cc * 8;
        dstB[i] = c * 8;
    }

    auto stage = [&](int buf, int kbase) {
#pragma unroll
        for (int i = 0; i < 2; ++i)
            load16(srcA[i] + kbase, &As[buf][dstA[i]]);
#pragma unroll
        for (int i = 0; i < 3; ++i)
            load16(srcB[i] + kbase, &Bs[buf][dstB[i]]);
    };

    int offA[4][2], offB[3][2];
#pragma unroll
    for (int mi = 0; mi < 4; ++mi) {
        const int row = wm + mi * 16 + r15;
#pragma unroll
        for (int ks = 0; ks < 2; ++ks)
            offA[mi][ks] = row * 64 + (((ks << 2) + qa) ^ (row & 7)) * 8;
    }
#pragma unroll
    for (int ni = 0; ni < 3; ++ni) {
        const int row = wn + ni * 16 + r15;
#pragma unroll
        for (int ks = 0; ks < 2; ++ks)
            offB[ni][ks] = row * 64 + (((ks << 2) + qa) ^ (row & 7)) * 8;
    }

    f32x4 acc[4][3];
#pragma unroll
    for (int i = 0; i < 4; ++i)
#pragma unroll
        for (int j = 0; j < 3; ++j) acc[i][j] = (f32x4){0.f, 0.f, 0.f, 0.f};

    stage(0, 0);
    stage(1, 64);
    stage(2, 128);

    int b = 0;
    for (int tt = 0; tt < NT; ++tt) {
        if (tt < NT - 2) {
            asm volatile("s_waitcnt vmcnt(10)" ::: "memory");
        } else if (tt == NT - 2) {
            asm volatile("s_waitcnt vmcnt(5)" ::: "memory");
        } else {
            asm volatile("s_waitcnt vmcnt(0)" ::: "memory");
        }
        __builtin_amdgcn_s_barrier();

#pragma unroll
        for (int ks = 0; ks < 2; ++ks) {
            bf16x8 aA[4], bB[3];
#pragma unroll
            for (int i = 0; i < 4; ++i)
                aA[i] = *(const bf16x8*)&As[b][offA[i][ks]];
#pragma unroll
            for (int ni = 0; ni < 3; ++ni)
                bB[ni] = *(const bf16x8*)&Bs[b][offB[ni][ks]];
#pragma unroll
            for (int i = 0; i < 4; ++i)
#pragma unroll
                for (int ni = 0; ni < 3; ++ni)
                    acc[i][ni] = __builtin_amdgcn_mfma_f32_16x16x32_bf16(
                        aA[i], bB[ni], acc[i][ni], 0, 0, 0);
        }

        asm volatile("" ::: "memory");
        __builtin_amdgcn_s_barrier();

        if (tt + 3 < NT) stage(b, (tt + 3) << 6);
        b = (b == 2) ? 0 : b + 1;
    }

    // epilogue: divide by denominator, write fp32 out
    const int cr = (lane >> 4) * 4;
#pragma unroll
    for (int mi = 0; mi < 4; ++mi) {
        const int gm = m0 + wm + mi * 16 + cr;
        const float i0 = 1.f / ls[gm + 0];
        const float i1 = 1.f / ls[gm + 1];
        const float i2 = 1.f / ls[gm + 2];
        const float i3 = 1.f / ls[gm + 3];
#pragma unroll
        for (int ni = 0; ni < 3; ++ni) {
            const int gn = n0 + wn + ni * 16 + r15;
            C[(size_t)(gm + 0) * 768 + gn] = acc[mi][ni][0] * i0;
            C[(size_t)(gm + 1) * 768 + gn] = acc[mi][ni][1] * i1;
            C[(size_t)(gm + 2) * 768 + gn] = acc[mi][ni][2] * i2;
            C[(size_t)(gm + 3) * 768 + gn] = acc[mi][ni][3] * i3;
        }
    }
}

// ---------------------------------------------------------------------------
extern "C" void kernel_launch(void* const* d_in, const int* in_sizes, int n_in,
                              void* d_out, int out_size, void* d_ws, size_t ws_size,
                              hipStream_t stream) {
    const float* x  = (const float*)d_in[0];   // [2,4096,768]
    const float* Wq = (const float*)d_in[1];   // [768,768]
    const float* Wk = (const float*)d_in[2];
    const float* Wv = (const float*)d_in[3];
    float* out = (float*)d_out;                // [2,4096,768] fp32

    char* base = (char*)d_ws;
    size_t off = 0;
    auto alloc = [&](size_t b) { char* p = base + off; off += (b + 255) & ~(size_t)255; return p; };

    unsigned short* Xbf = (unsigned short*)alloc(8192ull * 768 * 2);   // x as bf16
    unsigned short* WqT = (unsigned short*)alloc(768ull * 768 * 2);    // W^T bf16, x3 contiguous
    unsigned short* WkT = (unsigned short*)alloc(768ull * 768 * 2);
    unsigned short* WvT = (unsigned short*)alloc(768ull * 768 * 2);
    unsigned short* Qb  = (unsigned short*)alloc(8192ull * 768 * 2);   // Q bf16
    unsigned short* Kb  = (unsigned short*)alloc(8192ull * 768 * 2);   // K bf16
    unsigned short* Vt  = (unsigned short*)alloc(768ull * 8192 * 2);   // V^T bf16 [768,8192]
    unsigned short* Sexp = (unsigned short*)alloc(2ull * 4096 * 4096 * 2); // exp(scores) bf16
    float* lsum = (float*)alloc(2ull * 4096 * 4);                      // softmax denominators
    (void)ws_size; (void)in_sizes; (void)n_in; (void)out_size; (void)WkT; (void)WvT;

    // 1) x -> bf16, W -> W^T bf16, lsum <- 0
    prep<<<dim3(3265), dim3(1024), 0, stream>>>(x, Xbf, Wq, Wk, Wv, WqT, WkT, WvT, lsum);
    // 2) Q and K in one exact-fill 256-block launch (B = WqT||WkT stacked)
    qk2<<<dim3(256), dim3(512), 0, stream>>>(Xbf, WqT, Qb, Kb);
    // 3) V^T, 256 blocks exact fill
    vt2<<<dim3(256), dim3(512), 0, stream>>>(WvT, Xbf, Vt);
    // 4) Sexp = exp(Q.K^T / sqrt(768)) bf16 + fused f32 row sums (no VGPR cap)
    gemm_s_exp2<<<dim3(512), dim3(512), 0, stream>>>(
        Qb, Kb, Sexp, lsum, 0.03608439182435161f);
    // 5) out = (Sexp . V) / lsum, fp32
    gemm_out<<<dim3(256), dim3(512), 0, stream>>>(Sexp, Vt, lsum, out);
}